// Round 1
// baseline (3428.471 us; speedup 1.0000x reference)
//
#include <hip/hip_runtime.h>
#include <stdint.h>

// LSTM  B=128, S=256, I=1024, H=1024
// Phase 1: gates_x = x @ Wx^T + b   (parallel GEMM, bf16 MFMA, m97-style)
// Phase 2: 256 sequential fused steps: pre = gates_x[s] + h @ Wh^T ; cell update.
//
// Workspace layout (bytes):
//   Xc    bf16 [S*B][I]      67,108,864   @ 0          (row m = s*128 + b)
//   Whp   bf16 [4H][H]        8,388,608   @ 67,108,864 (n = gate*1024 + h; f,i,g,o)
//   Wxp   bf16 [4H][I]        8,388,608   @ 75,497,472
//   biasp f32  [4H]              16,384   @ 83,886,080
//   h2    bf16 2*[128][1024]    524,288   @ 83,902,464 (ping-pong)
//   cws   f32  [128][1024]      524,288   @ 84,426,752
//   gx    bf16 [4096][4096]  33,554,432   @ 84,951,040 (one 32-step chunk)
// total 118,505,472

typedef unsigned short u16;
typedef unsigned int u32;
typedef __bf16 bf16x8 __attribute__((ext_vector_type(8)));
typedef float f32x4 __attribute__((ext_vector_type(4)));

__device__ __forceinline__ u16 f2bf(float f) {
  u32 u = __builtin_bit_cast(u32, f);
  u = (u + 0x7fffu + ((u >> 16) & 1u)) >> 16;
  return (u16)u;
}
__device__ __forceinline__ float bf2f(u16 s) {
  u32 u = ((u32)s) << 16;
  return __builtin_bit_cast(float, u);
}
__device__ __forceinline__ u32 pack2bf(float a, float b) {
  return (u32)f2bf(a) | ((u32)f2bf(b) << 16);
}

// async global -> LDS, 16B per lane. LDS dest must be wave-uniform base + lane*16.
__device__ __forceinline__ void gl2lds16(const void* gptr, void* lptr) {
  __builtin_amdgcn_global_load_lds(
      (__attribute__((address_space(1))) void*)(uintptr_t)gptr,
      (__attribute__((address_space(3))) void*)(uintptr_t)lptr, 16, 0, 0);
}

__device__ __forceinline__ float sigm(float x) { return 1.f / (1.f + __expf(-x)); }
__device__ __forceinline__ float tanh_f(float x) { return 2.f / (1.f + __expf(-2.f * x)) - 1.f; }

// ---------------- pack / convert kernels ----------------

// x [B][S][I] f32 -> Xc bf16 [S*B][I] with row m = s*128 + b
__global__ __launch_bounds__(256) void convert_x(const float* __restrict__ x, u16* __restrict__ Xc) {
  int t = blockIdx.x * 256 + threadIdx.x;  // 0..4194303
  int i8 = t & 127;
  int s = (t >> 7) & 255;
  int b = t >> 15;
  const float4* src = (const float4*)(x + (((b << 8) + s) << 10) + (i8 << 3));
  float4 a = src[0], c = src[1];
  uint4 o;
  o.x = pack2bf(a.x, a.y); o.y = pack2bf(a.z, a.w);
  o.z = pack2bf(c.x, c.y); o.w = pack2bf(c.z, c.w);
  *(uint4*)(Xc + (((s << 7) + b) << 10) + (i8 << 3)) = o;
}

__global__ __launch_bounds__(256) void pack_w(const float* __restrict__ Wf, const float* __restrict__ Wi,
                                              const float* __restrict__ Wc, const float* __restrict__ Wo,
                                              u16* __restrict__ Whp, u16* __restrict__ Wxp) {
  int t = blockIdx.x * 256 + threadIdx.x;  // 0..524287
  int k8 = t & 127, n = t >> 7;
  int g = n >> 10, h = n & 1023;
  const float* W = (g == 0) ? Wf : (g == 1) ? Wi : (g == 2) ? Wc : Wo;
  const float4* ph = (const float4*)(W + h * 2048 + (k8 << 3));
  float4 a = ph[0], b = ph[1];
  uint4 oh;
  oh.x = pack2bf(a.x, a.y); oh.y = pack2bf(a.z, a.w);
  oh.z = pack2bf(b.x, b.y); oh.w = pack2bf(b.z, b.w);
  *(uint4*)(Whp + n * 1024 + (k8 << 3)) = oh;
  const float4* px = (const float4*)(W + h * 2048 + 1024 + (k8 << 3));
  float4 c = px[0], d = px[1];
  uint4 ox;
  ox.x = pack2bf(c.x, c.y); ox.y = pack2bf(c.z, c.w);
  ox.z = pack2bf(d.x, d.y); ox.w = pack2bf(d.z, d.w);
  *(uint4*)(Wxp + n * 1024 + (k8 << 3)) = ox;
}

__global__ __launch_bounds__(256) void pack_b(const float* __restrict__ bf_, const float* __restrict__ bi,
                                              const float* __restrict__ bc, const float* __restrict__ bo,
                                              float* __restrict__ biasp) {
  int n = blockIdx.x * 256 + threadIdx.x;  // 0..4095
  int g = n >> 10, h = n & 1023;
  const float* b = (g == 0) ? bf_ : (g == 1) ? bi : (g == 2) ? bc : bo;
  biasp[n] = b[h];
}

// ---------------- phase 1 GEMM: gx = Xc @ Wxp^T + bias ----------------
// 128x128 tile, BK=64, single LDS buffer, 2 barriers/iter (m97 structure),
// XOR swizzle (c8 ^ (row&7)) for conflict-free ds_read_b128 frag loads.
__global__ __launch_bounds__(256) void gemm_x(const u16* __restrict__ A,   // Xc [32768][1024]
                                              const u16* __restrict__ Bw,  // Wxp [4096][1024]
                                              const float* __restrict__ bias,
                                              u16* __restrict__ gx,  // [4096][4096] chunk-local
                                              int m_base) {
  __shared__ __align__(16) u16 lds_a[128 * 64];
  __shared__ __align__(16) u16 lds_b[128 * 64];
  const int tid = threadIdx.x;
  const int lane = tid & 63, q = lane >> 4, cl = lane & 15;
  const int w = tid >> 6, wm = w & 1, wn = w >> 1;
  const int m0 = m_base + blockIdx.y * 128;
  const int n0 = blockIdx.x * 128;
  f32x4 acc[4][4] = {};

  for (int it = 0; it < 16; ++it) {
    const int k0 = it * 64;
#pragma unroll
    for (int itn = 0; itn < 4; ++itn) {  // A: 1024 chunks of 16B
      int j = itn * 256 + tid;
      int row = j >> 3, c8s = (j & 7) ^ (row & 7);
      gl2lds16(A + (m0 + row) * 1024 + k0 + c8s * 8, &lds_a[j * 8]);
    }
#pragma unroll
    for (int itn = 0; itn < 4; ++itn) {  // B: 1024 chunks
      int j = itn * 256 + tid;
      int row = j >> 3, c8s = (j & 7) ^ (row & 7);
      gl2lds16(Bw + (n0 + row) * 1024 + k0 + c8s * 8, &lds_b[j * 8]);
    }
    asm volatile("s_waitcnt vmcnt(0)" ::: "memory");
    __syncthreads();
#pragma unroll
    for (int kk = 0; kk < 2; ++kk) {
      bf16x8 af[4], bfr[4];
#pragma unroll
      for (int mt = 0; mt < 4; ++mt) {
        int row = wm * 64 + mt * 16 + cl;
        int c8 = (kk * 4 + q) ^ (row & 7);
        af[mt] = *(const bf16x8*)&lds_a[row * 64 + c8 * 8];
      }
#pragma unroll
      for (int nt = 0; nt < 4; ++nt) {
        int row = wn * 64 + nt * 16 + cl;
        int c8 = (kk * 4 + q) ^ (row & 7);
        bfr[nt] = *(const bf16x8*)&lds_b[row * 64 + c8 * 8];
      }
#pragma unroll
      for (int mt = 0; mt < 4; ++mt)
#pragma unroll
        for (int nt = 0; nt < 4; ++nt)
          acc[mt][nt] = __builtin_amdgcn_mfma_f32_16x16x32_bf16(af[mt], bfr[nt], acc[mt][nt], 0, 0, 0);
    }
    __syncthreads();
  }
  // epilogue: C[m][n], m = wm*64+mt*16+q*4+r, n = wn*64+nt*16+cl
#pragma unroll
  for (int nt = 0; nt < 4; ++nt) {
    int n = n0 + wn * 64 + nt * 16 + cl;
    float bv = bias[n];
#pragma unroll
    for (int mt = 0; mt < 4; ++mt) {
#pragma unroll
      for (int r = 0; r < 4; ++r) {
        int m_loc = blockIdx.y * 128 + wm * 64 + mt * 16 + q * 4 + r;
        gx[m_loc * 4096 + n] = f2bf(acc[mt][nt][r] + bv);
      }
    }
  }
}

// ---------------- phase 2: fused recurrent step ----------------
// grid (64, 2): blockIdx.x -> h0 = 16*bx (16 h-columns x 4 gates = 64 n), blockIdx.y -> m half (64 rows).
// K-loop double-buffered (1 block/CU: no inter-block latency hiding, so pipeline explicitly).
__global__ __launch_bounds__(256) void lstm_step(const u16* __restrict__ Whp,  // [4096][1024]
                                                 const u16* __restrict__ gx,   // [4096][4096]
                                                 const u16* __restrict__ h_in, // [128][1024]
                                                 u16* __restrict__ h_out,
                                                 float* __restrict__ cws,      // [128][1024]
                                                 float* __restrict__ out,      // [128][256][1024]
                                                 int s) {
  __shared__ __align__(16) u16 lds_a[2][64 * 64];
  __shared__ __align__(16) u16 lds_b[2][64 * 64];
  __shared__ float pre[64 * 65];  // [n_loc][m_loc], stride 65 kills bank conflicts
  const int tid = threadIdx.x;
  const int lane = tid & 63, q = lane >> 4, cl = lane & 15;
  const int w = tid >> 6, wm = w & 1, wn = w >> 1;
  const int h0 = blockIdx.x * 16;
  const int mh = blockIdx.y * 64;
  f32x4 acc[2][2] = {};

  // stage K-slice `it` (64 wide) into buffer `buf`
  auto stage = [&](int buf, int it) {
    const int k0 = it * 64;
#pragma unroll
    for (int itn = 0; itn < 2; ++itn) {  // A: 512 chunks
      int j = itn * 256 + tid;
      int row = j >> 3, c8s = (j & 7) ^ (row & 7);
      gl2lds16(h_in + (mh + row) * 1024 + k0 + c8s * 8, &lds_a[buf][j * 8]);
    }
#pragma unroll
    for (int itn = 0; itn < 2; ++itn) {  // B: 512 chunks, rows gathered across 4 gates
      int j = itn * 256 + tid;
      int row = j >> 3, c8s = (j & 7) ^ (row & 7);
      int ng = ((row >> 4) << 10) + h0 + (row & 15);
      gl2lds16(Whp + ng * 1024 + k0 + c8s * 8, &lds_b[buf][j * 8]);
    }
  };

  stage(0, 0);
  for (int it = 0; it < 16; ++it) {
    const int buf = it & 1;
    asm volatile("s_waitcnt vmcnt(0)" ::: "memory");
    __syncthreads();  // single barrier/iter: also protects buf^1 from overwrite
    if (it + 1 < 16) stage(buf ^ 1, it + 1);
#pragma unroll
    for (int kk = 0; kk < 2; ++kk) {
      bf16x8 af[2], bfr[2];
#pragma unroll
      for (int mt = 0; mt < 2; ++mt) {
        int row = wm * 32 + mt * 16 + cl;
        int c8 = (kk * 4 + q) ^ (row & 7);
        af[mt] = *(const bf16x8*)&lds_a[buf][row * 64 + c8 * 8];
      }
#pragma unroll
      for (int nt = 0; nt < 2; ++nt) {
        int row = wn * 32 + nt * 16 + cl;
        int c8 = (kk * 4 + q) ^ (row & 7);
        bfr[nt] = *(const bf16x8*)&lds_b[buf][row * 64 + c8 * 8];
      }
#pragma unroll
      for (int mt = 0; mt < 2; ++mt)
#pragma unroll
        for (int nt = 0; nt < 2; ++nt)
          acc[mt][nt] = __builtin_amdgcn_mfma_f32_16x16x32_bf16(af[mt], bfr[nt], acc[mt][nt], 0, 0, 0);
    }
  }
  // epilogue: pre[n_loc][m_loc] = acc + gates_x
#pragma unroll
  for (int mt = 0; mt < 2; ++mt) {
#pragma unroll
    for (int nt = 0; nt < 2; ++nt) {
      int n_loc = wn * 32 + nt * 16 + cl;
      int ng = ((n_loc >> 4) << 10) + h0 + (n_loc & 15);
#pragma unroll
      for (int r = 0; r < 4; ++r) {
        int m_loc = wm * 32 + mt * 16 + q * 4 + r;
        int grow = ((s & 31) << 7) + mh + m_loc;
        pre[n_loc * 65 + m_loc] = acc[mt][nt][r] + bf2f(gx[grow * 4096 + ng]);
      }
    }
  }
  __syncthreads();
  // cell update: 64 m x 16 h per block = 1024 cells, 4 per thread
#pragma unroll
  for (int i = 0; i < 4; ++i) {
    int lin = i * 256 + tid;
    int hl = lin & 15, m_loc = lin >> 4;
    int m = mh + m_loc;
    int hg = h0 + hl;
    float pf = pre[(hl) * 65 + m_loc];
    float pi = pre[(16 + hl) * 65 + m_loc];
    float pg = pre[(32 + hl) * 65 + m_loc];
    float po = pre[(48 + hl) * 65 + m_loc];
    float cold = cws[m * 1024 + hg];
    float fg = sigm(pf), ig = sigm(pi), gg = tanh_f(pg), og = sigm(po);
    float cn = cold * fg + ig * gg;
    float hn = tanh_f(cn) * og;
    cws[m * 1024 + hg] = cn;
    h_out[m * 1024 + hg] = f2bf(hn);
    out[(m * 256 + s) * 1024 + hg] = hn;
  }
}

// ---------------- launch ----------------

extern "C" void kernel_launch(void* const* d_in, const int* in_sizes, int n_in,
                              void* d_out, int out_size, void* d_ws, size_t ws_size,
                              hipStream_t stream) {
  const float* x   = (const float*)d_in[0];
  const float* Wf  = (const float*)d_in[1];
  const float* bf_ = (const float*)d_in[2];
  const float* Wi  = (const float*)d_in[3];
  const float* bi  = (const float*)d_in[4];
  const float* Wc  = (const float*)d_in[5];
  const float* bc  = (const float*)d_in[6];
  const float* Wo  = (const float*)d_in[7];
  const float* bo  = (const float*)d_in[8];
  float* out = (float*)d_out;
  char* ws = (char*)d_ws;

  const size_t NEEDED = 118505472;
  if (ws_size < NEEDED) return;  // fail cleanly (wrong output) instead of faulting

  u16*  Xc    = (u16*)(ws);
  u16*  Whp   = (u16*)(ws + 67108864);
  u16*  Wxp   = (u16*)(ws + 75497472);
  float* biasp = (float*)(ws + 83886080);
  u16*  h2    = (u16*)(ws + 83902464);   // 2 x 131072 bf16
  float* cws  = (float*)(ws + 84426752);
  u16*  gx    = (u16*)(ws + 84951040);

  // zero h (both buffers) + c
  hipMemsetAsync(ws + 83902464, 0, 1048576, stream);
  convert_x<<<16384, 256, 0, stream>>>(x, Xc);
  pack_w<<<2048, 256, 0, stream>>>(Wf, Wi, Wc, Wo, Whp, Wxp);
  pack_b<<<16, 256, 0, stream>>>(bf_, bi, bc, bo, biasp);

  for (int c = 0; c < 8; ++c) {
    gemm_x<<<dim3(32, 32), 256, 0, stream>>>(Xc, Wxp, biasp, gx, c * 4096);
    for (int t = 0; t < 32; ++t) {
      int s = c * 32 + t;
      lstm_step<<<dim3(64, 2), 256, 0, stream>>>(
          Whp, gx, h2 + (s & 1) * 131072, h2 + ((s + 1) & 1) * 131072, cws, out, s);
    }
  }
}